// Round 15
// baseline (573.876 us; speedup 1.0000x reference)
//
#include <hip/hip_runtime.h>
#include <hip/hip_bf16.h>

#ifndef MIN
#define MIN(a,b) ((a)<(b)?(a):(b))
#endif

#define RFL(x) __builtin_amdgcn_readfirstlane(x)

typedef __attribute__((ext_vector_type(8))) short bf16x8;
typedef __attribute__((ext_vector_type(4))) float f32x4;

#define CAPC 96
#define CAPM 256
#define CAPT 16

__device__ __forceinline__ unsigned short f2bf(float f) {
    unsigned int u = __float_as_uint(f);
    u = (u + 0x7fffu + ((u >> 16) & 1u)) >> 16;      // RNE
    return (unsigned short)u;
}

// ---------------------------------------------------------------------------
// prep_wx: fragment-ordered bf16 weights (unchanged).
// ---------------------------------------------------------------------------
__global__ __launch_bounds__(256)
void prep_wx(const float* __restrict__ w1dt, const float* __restrict__ b1t,
             const float* __restrict__ w1st, const float* __restrict__ w2r,
             unsigned short* __restrict__ wsumf, unsigned short* __restrict__ w2f)
{
    const int t = blockIdx.x * 256 + threadIdx.x;
    if (t < 768) {
        const int lane = t & 63, nblk = (t >> 6) & 3, kstep = t >> 8;
        const int c = nblk * 16 + (lane & 15);
        unsigned short h[8];
#pragma unroll
        for (int j = 0; j < 8; ++j) {
            const int k = kstep * 32 + ((lane >> 4) << 3) + j;
            float v = 0.f;
            if (k < 85)       v = w1dt[k * 64 + c] + w1dt[85 * 64 + k * 64 + c];
            else if (k == 85) v = w1st[c];
            else if (k == 86) v = w1st[64 + c];
            else if (k == 87) v = b1t[c] + b1t[64 + c];
            h[j] = f2bf(v);
        }
        unsigned short* dst = wsumf + (size_t)((kstep * 4 + nblk) * 64 + lane) * 8;
#pragma unroll
        for (int j = 0; j < 8; ++j) dst[j] = h[j];
    } else if (t < 768 + 1024) {
        const int t2 = t - 768;
        const int lane = t2 & 63, nblk = (t2 >> 6) & 3, kstep = (t2 >> 8) & 1, rel = t2 >> 9;
        const int c = nblk * 16 + (lane & 15);
        unsigned short h[8];
#pragma unroll
        for (int j = 0; j < 8; ++j) {
            const int k = kstep * 32 + ((lane >> 4) << 3) + j;
            h[j] = f2bf(w2r[rel * 4096 + k * 64 + c]);
        }
        unsigned short* dst = w2f + (size_t)((((rel * 2 + kstep) * 4) + nblk) * 64 + lane) * 8;
#pragma unroll
        for (int j = 0; j < 8; ++j) dst[j] = h[j];
    }
}

// ---------------------------------------------------------------------------
// prep_x_main: x_trans fp32 [Nt][85] -> bf16 padded [NtP][96] (unchanged).
// ---------------------------------------------------------------------------
__global__ __launch_bounds__(256)
void prep_x_main(const float* __restrict__ xt, int Nt, int NtP,
                 unsigned short* __restrict__ xbf)
{
    const long total = (long)NtP * 12;
    const long stride = (long)gridDim.x * 256;
    for (long u = (long)blockIdx.x * 256 + threadIdx.x; u < total; u += stride) {
        const int row = (int)(u / 12), g = (int)(u % 12);
        const bool real = row < Nt;
        unsigned int w[4];
        const float* src = xt + (size_t)row * 85;
#pragma unroll
        for (int p = 0; p < 4; ++p) {
            const int k0 = g * 8 + p * 2, k1 = k0 + 1;
            float v0 = 0.f, v1 = 0.f;
            if (real) {
                if (k0 < 85) v0 = src[k0]; else if (k0 == 87) v0 = 1.f;
                if (k1 < 85) v1 = src[k1]; else if (k1 == 87) v1 = 1.f;
            }
            w[p] = (unsigned int)f2bf(v0) | ((unsigned int)f2bf(v1) << 16);
        }
        uint4* dst = reinterpret_cast<uint4*>(xbf + (size_t)row * 96 + g * 8);
        *dst = make_uint4(w[0], w[1], w[2], w[3]);
    }
}

// ---------------------------------------------------------------------------
// prep_x_agg: scalar conv1 aggregates via GATHER over trans-side ushort
// buckets. x_card/x_merch are LLC-resident.
// ---------------------------------------------------------------------------
__global__ __launch_bounds__(256)
void prep_x_agg(const float* __restrict__ x_card, const float* __restrict__ x_merch,
                const int* __restrict__ cnt, const unsigned short* __restrict__ adjT,
                int Nc, int Nm, int Nt, unsigned short* __restrict__ xbf)
{
    const int stride = gridDim.x * 256;
    const int b0 = Nc + Nm, b1 = Nc + Nm + Nt;
    for (int r = blockIdx.x * 256 + threadIdx.x; r < Nt; r += stride) {
        float a = 0.f;
        {
            const int n = MIN(cnt[b0 + r], CAPT);
            const unsigned short* s = adjT + (size_t)r * CAPT;
            for (int j = 0; j < n; ++j) a += x_card[s[j]];
        }
        float b = 0.f;
        {
            const int n = MIN(cnt[b1 + r], CAPT);
            const unsigned short* s = adjT + (size_t)(Nt + r) * CAPT;
            for (int j = 0; j < n; ++j) b += x_merch[s[j]];
        }
        xbf[(size_t)r * 96 + 85] = f2bf(a);
        xbf[(size_t)r * 96 + 86] = f2bf(b);
    }
}

// ---------------------------------------------------------------------------
// fill: bucketed CSR, 8 scattered ops/edge (unchanged from R14).
// ---------------------------------------------------------------------------
__global__ __launch_bounds__(256)
void fill(const int* __restrict__ sp, const int* __restrict__ dp,
          const int* __restrict__ sr, const int* __restrict__ dr,
          int E, int Nc, int Nm, int Nt,
          int* __restrict__ cnt, int* __restrict__ adj,
          unsigned short* __restrict__ adjT, int baseM)
{
    const int tid    = blockIdx.x * 256 + threadIdx.x;
    const int stride = gridDim.x * 256;
    for (int e0 = tid; e0 < E; e0 += 4 * stride) {
        int vsp[4], vdp[4], vsr[4], vdr[4];
        bool act[4];
#pragma unroll
        for (int u = 0; u < 4; ++u) {
            const int e = e0 + u * stride;
            act[u] = (e < E);
            const int ee = act[u] ? e : e0;
            vsp[u] = sp[ee]; vdp[u] = dp[ee];
            vsr[u] = sr[ee]; vdr[u] = dr[ee];
        }
        int pc[4], pm[4], pp[4], pr[4];
#pragma unroll
        for (int u = 0; u < 4; ++u) if (act[u]) pc[u] = atomicAdd(&cnt[vsp[u]], 1);
#pragma unroll
        for (int u = 0; u < 4; ++u) if (act[u]) pm[u] = atomicAdd(&cnt[Nc + vsr[u]], 1);
#pragma unroll
        for (int u = 0; u < 4; ++u) if (act[u]) pp[u] = atomicAdd(&cnt[Nc + Nm + vdp[u]], 1);
#pragma unroll
        for (int u = 0; u < 4; ++u) if (act[u]) pr[u] = atomicAdd(&cnt[Nc + Nm + Nt + vdr[u]], 1);
#pragma unroll
        for (int u = 0; u < 4; ++u)
            if (act[u] && pc[u] < CAPC) adj[vsp[u] * CAPC + pc[u]] = vdp[u];
#pragma unroll
        for (int u = 0; u < 4; ++u)
            if (act[u] && pm[u] < CAPM) adj[baseM + vsr[u] * CAPM + pm[u]] = vdr[u];
#pragma unroll
        for (int u = 0; u < 4; ++u)
            if (act[u] && pp[u] < CAPT)
                adjT[(size_t)vdp[u] * CAPT + pp[u]] = (unsigned short)vsp[u];
#pragma unroll
        for (int u = 0; u < 4; ++u)
            if (act[u] && pr[u] < CAPT)
                adjT[(size_t)(Nt + vdr[u]) * CAPT + pr[u]] = (unsigned short)vsr[u];
    }
}

// ---------------------------------------------------------------------------
// gather85: per card/merchant node, sum xbf (bf16, 192B rows) over edge list.
// 4-way unrolled row streams for MLP (merchant avg degree ~50).
// ---------------------------------------------------------------------------
__global__ __launch_bounds__(256)
void gather85(const unsigned short* __restrict__ xbf,
              const int* __restrict__ cnt, const int* __restrict__ adj,
              int Nc, int Nm, int baseM,
              float* __restrict__ aggC, float* __restrict__ aggM)
{
    const int lane = threadIdx.x & 63;
    const int gw   = blockIdx.x * (blockDim.x >> 6) + (threadIdx.x >> 6);
    const int nw   = gridDim.x * (blockDim.x >> 6);
    const int N = Nc + Nm;
    for (int i = gw; i < N; i += nw) {
        int n, base;
        if (i < Nc) { n = MIN(cnt[i], CAPC); base = i * CAPC; }
        else        { n = MIN(cnt[i], CAPM); base = baseM + (i - Nc) * CAPM; }
        float a0 = 0.f, a1 = 0.f, b0 = 0.f, b1 = 0.f;
        float c0 = 0.f, c1 = 0.f, d0 = 0.f, d1 = 0.f;
        int j = 0;
        for (; j + 3 < n; j += 4) {
            const unsigned int* r0 = reinterpret_cast<const unsigned int*>(
                xbf + (size_t)adj[base + j] * 96);
            const unsigned int* r1 = reinterpret_cast<const unsigned int*>(
                xbf + (size_t)adj[base + j + 1] * 96);
            const unsigned int* r2 = reinterpret_cast<const unsigned int*>(
                xbf + (size_t)adj[base + j + 2] * 96);
            const unsigned int* r3 = reinterpret_cast<const unsigned int*>(
                xbf + (size_t)adj[base + j + 3] * 96);
            if (lane < 43) {
                const unsigned int u0 = r0[lane], u1 = r1[lane];
                const unsigned int u2 = r2[lane], u3 = r3[lane];
                a0 += __uint_as_float((u0 & 0xffffu) << 16);
                b0 += __uint_as_float((u1 & 0xffffu) << 16);
                c0 += __uint_as_float((u2 & 0xffffu) << 16);
                d0 += __uint_as_float((u3 & 0xffffu) << 16);
                if (lane < 42) {
                    a1 += __uint_as_float(u0 & 0xffff0000u);
                    b1 += __uint_as_float(u1 & 0xffff0000u);
                    c1 += __uint_as_float(u2 & 0xffff0000u);
                    d1 += __uint_as_float(u3 & 0xffff0000u);
                }
            }
        }
        for (; j < n; ++j) {
            const unsigned int* r0 = reinterpret_cast<const unsigned int*>(
                xbf + (size_t)adj[base + j] * 96);
            if (lane < 43) {
                const unsigned int u0 = r0[lane];
                a0 += __uint_as_float((u0 & 0xffffu) << 16);
                if (lane < 42) a1 += __uint_as_float(u0 & 0xffff0000u);
            }
        }
        a0 += b0; c0 += d0; a0 += c0;
        a1 += b1; c1 += d1; a1 += c1;
        float* dst = (i < Nc) ? aggC + (size_t)i * 85 : aggM + (size_t)(i - Nc) * 85;
        if (lane < 43) dst[2 * lane] = a0;
        if (lane < 42) dst[2 * lane + 1] = a1;
    }
}

// ---------------------------------------------------------------------------
// fused_small (unchanged): aggT -> h -> z
// ---------------------------------------------------------------------------
__global__ __launch_bounds__(256, 7)
void fused_small(const float* __restrict__ in, int M,
                 const float* __restrict__ Wsum,   // [85][64]
                 const float* __restrict__ bsum,   // [64]
                 const float* __restrict__ s1, const float* __restrict__ wv1,
                 const float* __restrict__ W2,     // [64][64]
                 float* __restrict__ out0)
{
    constexpr int K = 85;
    __shared__ float xbuf[64 * K];
    const int tid  = threadIdx.x;
    const int lane = tid & 63;
    const int wid  = tid >> 6;
    const int c0   = RFL(wid * 16);

    const int ntiles = (M + 63) >> 6;
    for (int t = blockIdx.x; t < ntiles; t += gridDim.x) {
        const int base = t << 6;
        const int rows = MIN(64, M - base);
        __syncthreads();
        {
            const int nw = rows * K;
            const float4* s4 = reinterpret_cast<const float4*>(in + (size_t)base * K);
            const int nv = nw >> 2;
            for (int i = tid; i < nv; i += 256)
                reinterpret_cast<float4*>(xbuf)[i] = s4[i];
            for (int i = (nv << 2) + tid; i < nw; i += 256)
                xbuf[i] = in[(size_t)base * K + i];
        }
        __syncthreads();
        float acc[16];
#pragma unroll
        for (int j = 0; j < 16; ++j) acc[j] = bsum[c0 + j];
        {
            const float sv1 = (lane < rows) ? s1[base + lane] : 0.f;
#pragma unroll
            for (int j = 0; j < 16; ++j) acc[j] = fmaf(sv1, wv1[c0 + j], acc[j]);
        }
        {
            const float* xr = xbuf + lane * K;
#pragma unroll 5
            for (int k = 0; k < K; ++k) {
                const float xk = xr[k];
                const float* wk = Wsum + k * 64 + c0;
#pragma unroll
                for (int j = 0; j < 16; ++j) acc[j] = fmaf(xk, wk[j], acc[j]);
            }
        }
        __syncthreads();
#pragma unroll
        for (int j = 0; j < 16; ++j) xbuf[lane * K + c0 + j] = fmaxf(acc[j], 0.f);
        __syncthreads();
        float a2[16];
#pragma unroll
        for (int j = 0; j < 16; ++j) a2[j] = 0.f;
        {
            const float* hr = xbuf + lane * K;
#pragma unroll 4
            for (int k = 0; k < 64; ++k) {
                const float hk = hr[k];
                const float* wk = W2 + k * 64 + c0;
#pragma unroll
                for (int j = 0; j < 16; ++j) a2[j] = fmaf(hk, wk[j], a2[j]);
            }
        }
        if (lane < rows) {
            float* o0 = out0 + (size_t)(base + lane) * 64 + c0;
#pragma unroll
            for (int j4 = 0; j4 < 4; ++j4)
                reinterpret_cast<float4*>(o0)[j4] =
                    make_float4(a2[4*j4], a2[4*j4+1], a2[4*j4+2], a2[4*j4+3]);
        }
    }
}

// ---------------------------------------------------------------------------
// mega_mfma: all-MFMA transaction pipeline. LDS 27136 B x 6 blocks = 162816 B
// fits in 160 KiB -> __launch_bounds__(256,6) raises occupancy 3.2->6 blk/CU.
// ---------------------------------------------------------------------------
__global__ __launch_bounds__(256, 6)
void mega_mfma(const unsigned short* __restrict__ xbf, int M,
               const unsigned short* __restrict__ wsumf,
               const unsigned short* __restrict__ w2f,
               const float* __restrict__ b2,     // [4][64], rel 0/1 used
               const float* __restrict__ z1, const float* __restrict__ z2,
               const int* __restrict__ cnt, const unsigned short* __restrict__ adjT,
               int zb0, int zb1, int Nt,
               const float* __restrict__ wl, const float* __restrict__ bl,
               float* __restrict__ out)
{
    __shared__ __align__(16) char ubuf[64 * 68 * 4];   // vbuf f32[64][68] | xb bf16[64][104]
    __shared__ __align__(16) unsigned short hbuf[64 * 72];
    __shared__ float obuf[64][2];
    unsigned short* xb = (unsigned short*)ubuf;
    float*          vbuf = (float*)ubuf;

    const int tid  = threadIdx.x;
    const int lane = tid & 63;
    const int wid  = tid >> 6;
    const int c0   = RFL(wid * 16);
    const bf16x8* wsv = reinterpret_cast<const bf16x8*>(wsumf);
    const bf16x8* w2v = reinterpret_cast<const bf16x8*>(w2f);

    const int ntiles = (M + 63) >> 6;
    for (int t = blockIdx.x; t < ntiles; t += gridDim.x) {
        const int base = t << 6;
        const int rows = MIN(64, M - base);
        __syncthreads();
        // ---- stage: 64 rows x 96 bf16 (12 KB), coalesced 16B units ----
        for (int u = tid; u < 768; u += 256) {
            const int row = u / 12, g = u - row * 12;
            const uint4 d = *reinterpret_cast<const uint4*>(
                xbf + (size_t)(base + row) * 96 + g * 8);
            *reinterpret_cast<uint4*>(xb + row * 104 + g * 8) = d;
        }
        if (tid < 128) ((float*)obuf)[tid] = 0.f;
        __syncthreads();
        // ---- phase 1: acc1 = X~ @ Wsum~  (3 K-steps) ----
        f32x4 acc1[4];
#pragma unroll
        for (int nb = 0; nb < 4; ++nb) acc1[nb] = (f32x4){0.f, 0.f, 0.f, 0.f};
#pragma unroll
        for (int ks = 0; ks < 3; ++ks) {
            const bf16x8 af = *reinterpret_cast<const bf16x8*>(
                xb + (16 * wid + (lane & 15)) * 104 + ks * 32 + ((lane >> 4) << 3));
#pragma unroll
            for (int nb = 0; nb < 4; ++nb) {
                const bf16x8 bf = wsv[(ks * 4 + nb) * 64 + lane];
                acc1[nb] = __builtin_amdgcn_mfma_f32_16x16x32_bf16(af, bf, acc1[nb], 0, 0, 0);
            }
        }
        // ---- H = relu(acc1) -> hbuf bf16 [64][72] (GLOBAL row = 16*wid + local)
#pragma unroll
        for (int nb = 0; nb < 4; ++nb) {
#pragma unroll
            for (int i = 0; i < 4; ++i) {
                const int r = 16 * wid + ((lane >> 4) << 2) + i;
                const int c = (lane & 15) + 16 * nb;
                hbuf[r * 72 + c] = f2bf(fmaxf(acc1[nb][i], 0.f));
            }
        }
        __syncthreads();   // H visible; xb dead (vbuf may overwrite)
        // ---- per relation: phase 2 + transpose + row-pass ----
#pragma unroll 1
        for (int rel = 0; rel < 2; ++rel) {
            f32x4 acc2[4];
#pragma unroll
            for (int nb = 0; nb < 4; ++nb) {
                const float bv = b2[rel * 64 + (lane & 15) + 16 * nb];
                acc2[nb] = (f32x4){bv, bv, bv, bv};
            }
#pragma unroll
            for (int ks = 0; ks < 2; ++ks) {
                const bf16x8 af = *reinterpret_cast<const bf16x8*>(
                    hbuf + (16 * wid + (lane & 15)) * 72 + ks * 32 + ((lane >> 4) << 3));
#pragma unroll
                for (int nb = 0; nb < 4; ++nb) {
                    const bf16x8 bf = w2v[(((rel * 2 + ks) * 4) + nb) * 64 + lane];
                    acc2[nb] = __builtin_amdgcn_mfma_f32_16x16x32_bf16(af, bf, acc2[nb], 0, 0, 0);
                }
            }
            // transpose acc2 -> vbuf [row][col] (pitch 68), GLOBAL row
#pragma unroll
            for (int nb = 0; nb < 4; ++nb) {
#pragma unroll
                for (int i = 0; i < 4; ++i) {
                    const int r = 16 * wid + ((lane >> 4) << 2) + i;
                    const int c = (lane & 15) + 16 * nb;
                    vbuf[r * 68 + c] = acc2[nb][i];
                }
            }
            __syncthreads();
            // row-pass: lane = row, wave covers cols c0..c0+15
            float v[16];
            {
                const float* vr = vbuf + lane * 68 + c0;
#pragma unroll
                for (int q = 0; q < 4; ++q) {
                    const float4 t4 = reinterpret_cast<const float4*>(vr)[q];
                    v[4*q+0] = t4.x; v[4*q+1] = t4.y; v[4*q+2] = t4.z; v[4*q+3] = t4.w;
                }
            }
            if (lane < rows) {
                const int key = (rel ? zb1 : zb0) + base + lane;
                const int n = MIN(cnt[key], CAPT);
                const unsigned short* s = adjT +
                    (size_t)((rel ? Nt : 0) + base + lane) * CAPT;
                const float* zp = rel ? z2 : z1;
                for (int j = 0; j < n; ++j) {
                    const float4* zr = reinterpret_cast<const float4*>(
                        zp + (size_t)s[j] * 64 + c0);
#pragma unroll
                    for (int q = 0; q < 4; ++q) {
                        const float4 zv = zr[q];
                        v[4*q+0] += zv.x; v[4*q+1] += zv.y;
                        v[4*q+2] += zv.z; v[4*q+3] += zv.w;
                    }
                }
            }
            float pa = 0.f, pb = 0.f;
#pragma unroll
            for (int j = 0; j < 16; ++j) {
                const int c = rel * 64 + c0 + j;
                const float vv = fmaxf(v[j], 0.f);
                pa += vv * wl[c * 2 + 0];
                pb += vv * wl[c * 2 + 1];
            }
            atomicAdd(&obuf[lane][0], pa);
            atomicAdd(&obuf[lane][1], pb);
            __syncthreads();   // atomics done; vbuf reusable / obuf stable
        }
        if (tid < 2 * rows) {
            const int r = tid >> 1, o = tid & 1;
            out[(size_t)(base + r) * 2 + o] = obuf[r][o] + bl[o];
        }
    }
}

// ---------------------------------------------------------------------------
extern "C" void kernel_launch(void* const* d_in, const int* in_sizes, int n_in,
                              void* d_out, int out_size, void* d_ws, size_t ws_size,
                              hipStream_t stream)
{
    const float* x_card   = (const float*)d_in[0];
    const float* x_merch  = (const float*)d_in[1];
    const float* x_trans  = (const float*)d_in[2];
    const float* w1_src_t = (const float*)d_in[3];   // [2,1,64]
    const float* w1_dst_t = (const float*)d_in[4];   // [2,85,64]
    const float* b1_t     = (const float*)d_in[5];   // [2,64]
    const float* w1_src_r = (const float*)d_in[6];   // [2,85,64]
    const float* w1_dst_r = (const float*)d_in[7];   // [2,1,64]
    const float* b1_r     = (const float*)d_in[8];   // [2,64]
    const float* w2_l     = (const float*)d_in[9];   // [4,64,64]
    const float* w2_r     = (const float*)d_in[10];  // [4,64,64]
    const float* b2       = (const float*)d_in[11];  // [4,64]
    const float* w_lin    = (const float*)d_in[12];  // [128,2]
    const float* b_lin    = (const float*)d_in[13];  // [2]
    const int*   src_pays = (const int*)d_in[14];
    const int*   dst_pays = (const int*)d_in[15];
    const int*   src_recv = (const int*)d_in[16];
    const int*   dst_recv = (const int*)d_in[17];
    float*       out      = (float*)d_out;

    const int Nc = in_sizes[0];
    const int Nm = in_sizes[1];
    const int Nt = in_sizes[2] / 85;
    const int E  = in_sizes[14];
    const int Ntot = Nc + Nm + 2 * Nt;
    const int ntilesT = (Nt + 63) / 64;
    const int NtP = ntilesT * 64;

    const int baseM = Nc * CAPC;                       // int-bucket offset (merch)
    const size_t adjIntSlots = (size_t)baseM + (size_t)Nm * CAPM;
    const size_t adjTSlots   = (size_t)2 * Nt * CAPT;  // ushort trans buckets

    // workspace layout
    char* wsp = (char*)d_ws;
    auto alloc = [&](size_t bytes) -> void* {
        char* p = wsp;
        wsp += (bytes + 255) & ~(size_t)255;
        return (void*)p;
    };
    int*   cnt    = (int*)alloc((size_t)Ntot * 4);   // bucket cursors
    const size_t zero_bytes = (size_t)(wsp - (char*)d_ws);
    int*   adj    = (int*)alloc(adjIntSlots * 4);
    unsigned short* adjT = (unsigned short*)alloc(adjTSlots * 2);
    float* aggT_c = (float*)alloc((size_t)Nc * 85 * 4);
    float* aggT_m = (float*)alloc((size_t)Nm * 85 * 4);
    unsigned short* xbf   = (unsigned short*)alloc((size_t)NtP * 96 * 2);
    unsigned short* wsumf = (unsigned short*)alloc((size_t)3 * 4 * 64 * 8 * 2);
    unsigned short* w2f   = (unsigned short*)alloc((size_t)2 * 2 * 4 * 64 * 8 * 2);
    float* z1     = (float*)alloc((size_t)Nc * 64 * 4);
    float* z2     = (float*)alloc((size_t)Nm * 64 * 4);
    (void)ws_size; (void)n_in; (void)out_size;

    hipMemsetAsync(d_ws, 0, zero_bytes, stream);   // zero cnt only

    const dim3 blk(256);
    auto tiles = [](int M) { return (M + 63) / 64; };

    // weight fragments + padded bf16 x (slots 85/86 filled after fill)
    prep_wx<<<7, blk, 0, stream>>>(w1_dst_t, b1_t, w1_src_t, w2_r, wsumf, w2f);
    prep_x_main<<<2048, blk, 0, stream>>>(x_trans, Nt, NtP, xbf);

    // ---- bucketed CSR build (8 scattered ops/edge) ----
    fill<<<512, blk, 0, stream>>>(src_pays, dst_pays, src_recv, dst_recv, E, Nc, Nm, Nt,
                                  cnt, adj, adjT, baseM);
    // scalar aggregates by gather
    prep_x_agg<<<2048, blk, 0, stream>>>(x_card, x_merch, cnt, adjT, Nc, Nm, Nt, xbf);

    // ---- conv1 wide aggregation: wave per node, bf16 rows ----
    gather85<<<(Nc + Nm + 3) / 4, blk, 0, stream>>>(
        xbf, cnt, adj, Nc, Nm, baseM, aggT_c, aggT_m);

    // ---- small fused pipelines: aggT -> h -> z ----
    fused_small<<<tiles(Nc), blk, 0, stream>>>(
        aggT_c, Nc, w1_src_r, b1_r, x_card, w1_dst_r, w2_l, z1);
    fused_small<<<tiles(Nm), blk, 0, stream>>>(
        aggT_m, Nm, w1_src_r + 85 * 64, b1_r + 64, x_merch, w1_dst_r + 64,
        w2_l + 64 * 64, z2);

    // ---- MFMA megakernel ----
    mega_mfma<<<ntilesT, blk, 0, stream>>>(
        xbf, Nt, wsumf, w2f, b2, z1, z2,
        cnt, adjT, Nc + Nm, Nc + Nm + Nt, Nt,
        w_lin, b_lin, out);
}

// Round 16
// 513.194 us; speedup vs baseline: 1.1182x; 1.1182x over previous
//
#include <hip/hip_runtime.h>
#include <hip/hip_bf16.h>

#ifndef MIN
#define MIN(a,b) ((a)<(b)?(a):(b))
#endif

#define RFL(x) __builtin_amdgcn_readfirstlane(x)

typedef __attribute__((ext_vector_type(8))) short bf16x8;
typedef __attribute__((ext_vector_type(4))) float f32x4;

#define CAPC 96
#define CAPM 256
#define CAPT 16

__device__ __forceinline__ unsigned short f2bf(float f) {
    unsigned int u = __float_as_uint(f);
    u = (u + 0x7fffu + ((u >> 16) & 1u)) >> 16;      // RNE
    return (unsigned short)u;
}

// ---------------------------------------------------------------------------
// prep_wx: fragment-ordered bf16 weights (unchanged).
// ---------------------------------------------------------------------------
__global__ __launch_bounds__(256)
void prep_wx(const float* __restrict__ w1dt, const float* __restrict__ b1t,
             const float* __restrict__ w1st, const float* __restrict__ w2r,
             unsigned short* __restrict__ wsumf, unsigned short* __restrict__ w2f)
{
    const int t = blockIdx.x * 256 + threadIdx.x;
    if (t < 768) {
        const int lane = t & 63, nblk = (t >> 6) & 3, kstep = t >> 8;
        const int c = nblk * 16 + (lane & 15);
        unsigned short h[8];
#pragma unroll
        for (int j = 0; j < 8; ++j) {
            const int k = kstep * 32 + ((lane >> 4) << 3) + j;
            float v = 0.f;
            if (k < 85)       v = w1dt[k * 64 + c] + w1dt[85 * 64 + k * 64 + c];
            else if (k == 85) v = w1st[c];
            else if (k == 86) v = w1st[64 + c];
            else if (k == 87) v = b1t[c] + b1t[64 + c];
            h[j] = f2bf(v);
        }
        unsigned short* dst = wsumf + (size_t)((kstep * 4 + nblk) * 64 + lane) * 8;
#pragma unroll
        for (int j = 0; j < 8; ++j) dst[j] = h[j];
    } else if (t < 768 + 1024) {
        const int t2 = t - 768;
        const int lane = t2 & 63, nblk = (t2 >> 6) & 3, kstep = (t2 >> 8) & 1, rel = t2 >> 9;
        const int c = nblk * 16 + (lane & 15);
        unsigned short h[8];
#pragma unroll
        for (int j = 0; j < 8; ++j) {
            const int k = kstep * 32 + ((lane >> 4) << 3) + j;
            h[j] = f2bf(w2r[rel * 4096 + k * 64 + c]);
        }
        unsigned short* dst = w2f + (size_t)((((rel * 2 + kstep) * 4) + nblk) * 64 + lane) * 8;
#pragma unroll
        for (int j = 0; j < 8; ++j) dst[j] = h[j];
    }
}

// ---------------------------------------------------------------------------
// prep_x_main: x_trans fp32 [Nt][85] -> bf16 padded [NtP][96] (unchanged).
// ---------------------------------------------------------------------------
__global__ __launch_bounds__(256)
void prep_x_main(const float* __restrict__ xt, int Nt, int NtP,
                 unsigned short* __restrict__ xbf)
{
    const long total = (long)NtP * 12;
    const long stride = (long)gridDim.x * 256;
    for (long u = (long)blockIdx.x * 256 + threadIdx.x; u < total; u += stride) {
        const int row = (int)(u / 12), g = (int)(u % 12);
        const bool real = row < Nt;
        unsigned int w[4];
        const float* src = xt + (size_t)row * 85;
#pragma unroll
        for (int p = 0; p < 4; ++p) {
            const int k0 = g * 8 + p * 2, k1 = k0 + 1;
            float v0 = 0.f, v1 = 0.f;
            if (real) {
                if (k0 < 85) v0 = src[k0]; else if (k0 == 87) v0 = 1.f;
                if (k1 < 85) v1 = src[k1]; else if (k1 == 87) v1 = 1.f;
            }
            w[p] = (unsigned int)f2bf(v0) | ((unsigned int)f2bf(v1) << 16);
        }
        uint4* dst = reinterpret_cast<uint4*>(xbf + (size_t)row * 96 + g * 8);
        *dst = make_uint4(w[0], w[1], w[2], w[3]);
    }
}

// ---------------------------------------------------------------------------
// prep_x_agg: scalar conv1 aggregates via GATHER over trans-side ushort
// buckets. x_card/x_merch are LLC-resident.
// ---------------------------------------------------------------------------
__global__ __launch_bounds__(256)
void prep_x_agg(const float* __restrict__ x_card, const float* __restrict__ x_merch,
                const int* __restrict__ cnt, const unsigned short* __restrict__ adjT,
                int Nc, int Nm, int Nt, unsigned short* __restrict__ xbf)
{
    const int stride = gridDim.x * 256;
    const int b0 = Nc + Nm, b1 = Nc + Nm + Nt;
    for (int r = blockIdx.x * 256 + threadIdx.x; r < Nt; r += stride) {
        float a = 0.f;
        {
            const int n = MIN(cnt[b0 + r], CAPT);
            const unsigned short* s = adjT + (size_t)r * CAPT;
            for (int j = 0; j < n; ++j) a += x_card[s[j]];
        }
        float b = 0.f;
        {
            const int n = MIN(cnt[b1 + r], CAPT);
            const unsigned short* s = adjT + (size_t)(Nt + r) * CAPT;
            for (int j = 0; j < n; ++j) b += x_merch[s[j]];
        }
        xbf[(size_t)r * 96 + 85] = f2bf(a);
        xbf[(size_t)r * 96 + 86] = f2bf(b);
    }
}

// ---------------------------------------------------------------------------
// fill: bucketed CSR, 8 scattered ops/edge (unchanged from R14).
// ---------------------------------------------------------------------------
__global__ __launch_bounds__(256)
void fill(const int* __restrict__ sp, const int* __restrict__ dp,
          const int* __restrict__ sr, const int* __restrict__ dr,
          int E, int Nc, int Nm, int Nt,
          int* __restrict__ cnt, int* __restrict__ adj,
          unsigned short* __restrict__ adjT, int baseM)
{
    const int tid    = blockIdx.x * 256 + threadIdx.x;
    const int stride = gridDim.x * 256;
    for (int e0 = tid; e0 < E; e0 += 4 * stride) {
        int vsp[4], vdp[4], vsr[4], vdr[4];
        bool act[4];
#pragma unroll
        for (int u = 0; u < 4; ++u) {
            const int e = e0 + u * stride;
            act[u] = (e < E);
            const int ee = act[u] ? e : e0;
            vsp[u] = sp[ee]; vdp[u] = dp[ee];
            vsr[u] = sr[ee]; vdr[u] = dr[ee];
        }
        int pc[4], pm[4], pp[4], pr[4];
#pragma unroll
        for (int u = 0; u < 4; ++u) if (act[u]) pc[u] = atomicAdd(&cnt[vsp[u]], 1);
#pragma unroll
        for (int u = 0; u < 4; ++u) if (act[u]) pm[u] = atomicAdd(&cnt[Nc + vsr[u]], 1);
#pragma unroll
        for (int u = 0; u < 4; ++u) if (act[u]) pp[u] = atomicAdd(&cnt[Nc + Nm + vdp[u]], 1);
#pragma unroll
        for (int u = 0; u < 4; ++u) if (act[u]) pr[u] = atomicAdd(&cnt[Nc + Nm + Nt + vdr[u]], 1);
#pragma unroll
        for (int u = 0; u < 4; ++u)
            if (act[u] && pc[u] < CAPC) adj[vsp[u] * CAPC + pc[u]] = vdp[u];
#pragma unroll
        for (int u = 0; u < 4; ++u)
            if (act[u] && pm[u] < CAPM) adj[baseM + vsr[u] * CAPM + pm[u]] = vdr[u];
#pragma unroll
        for (int u = 0; u < 4; ++u)
            if (act[u] && pp[u] < CAPT)
                adjT[(size_t)vdp[u] * CAPT + pp[u]] = (unsigned short)vsp[u];
#pragma unroll
        for (int u = 0; u < 4; ++u)
            if (act[u] && pr[u] < CAPT)
                adjT[(size_t)(Nt + vdr[u]) * CAPT + pr[u]] = (unsigned short)vsr[u];
    }
}

// ---------------------------------------------------------------------------
// gather85: per card/merchant node, sum xbf (bf16, 192B rows) over edge list.
// 4-way unrolled row streams for MLP (merchant avg degree ~50).
// ---------------------------------------------------------------------------
__global__ __launch_bounds__(256)
void gather85(const unsigned short* __restrict__ xbf,
              const int* __restrict__ cnt, const int* __restrict__ adj,
              int Nc, int Nm, int baseM,
              float* __restrict__ aggC, float* __restrict__ aggM)
{
    const int lane = threadIdx.x & 63;
    const int gw   = blockIdx.x * (blockDim.x >> 6) + (threadIdx.x >> 6);
    const int nw   = gridDim.x * (blockDim.x >> 6);
    const int N = Nc + Nm;
    for (int i = gw; i < N; i += nw) {
        int n, base;
        if (i < Nc) { n = MIN(cnt[i], CAPC); base = i * CAPC; }
        else        { n = MIN(cnt[i], CAPM); base = baseM + (i - Nc) * CAPM; }
        float a0 = 0.f, a1 = 0.f, b0 = 0.f, b1 = 0.f;
        float c0 = 0.f, c1 = 0.f, d0 = 0.f, d1 = 0.f;
        int j = 0;
        for (; j + 3 < n; j += 4) {
            const unsigned int* r0 = reinterpret_cast<const unsigned int*>(
                xbf + (size_t)adj[base + j] * 96);
            const unsigned int* r1 = reinterpret_cast<const unsigned int*>(
                xbf + (size_t)adj[base + j + 1] * 96);
            const unsigned int* r2 = reinterpret_cast<const unsigned int*>(
                xbf + (size_t)adj[base + j + 2] * 96);
            const unsigned int* r3 = reinterpret_cast<const unsigned int*>(
                xbf + (size_t)adj[base + j + 3] * 96);
            if (lane < 43) {
                const unsigned int u0 = r0[lane], u1 = r1[lane];
                const unsigned int u2 = r2[lane], u3 = r3[lane];
                a0 += __uint_as_float((u0 & 0xffffu) << 16);
                b0 += __uint_as_float((u1 & 0xffffu) << 16);
                c0 += __uint_as_float((u2 & 0xffffu) << 16);
                d0 += __uint_as_float((u3 & 0xffffu) << 16);
                if (lane < 42) {
                    a1 += __uint_as_float(u0 & 0xffff0000u);
                    b1 += __uint_as_float(u1 & 0xffff0000u);
                    c1 += __uint_as_float(u2 & 0xffff0000u);
                    d1 += __uint_as_float(u3 & 0xffff0000u);
                }
            }
        }
        for (; j < n; ++j) {
            const unsigned int* r0 = reinterpret_cast<const unsigned int*>(
                xbf + (size_t)adj[base + j] * 96);
            if (lane < 43) {
                const unsigned int u0 = r0[lane];
                a0 += __uint_as_float((u0 & 0xffffu) << 16);
                if (lane < 42) a1 += __uint_as_float(u0 & 0xffff0000u);
            }
        }
        a0 += b0; c0 += d0; a0 += c0;
        a1 += b1; c1 += d1; a1 += c1;
        float* dst = (i < Nc) ? aggC + (size_t)i * 85 : aggM + (size_t)(i - Nc) * 85;
        if (lane < 43) dst[2 * lane] = a0;
        if (lane < 42) dst[2 * lane + 1] = a1;
    }
}

// ---------------------------------------------------------------------------
// fused_small (unchanged): aggT -> h -> z
// ---------------------------------------------------------------------------
__global__ __launch_bounds__(256, 7)
void fused_small(const float* __restrict__ in, int M,
                 const float* __restrict__ Wsum,   // [85][64]
                 const float* __restrict__ bsum,   // [64]
                 const float* __restrict__ s1, const float* __restrict__ wv1,
                 const float* __restrict__ W2,     // [64][64]
                 float* __restrict__ out0)
{
    constexpr int K = 85;
    __shared__ float xbuf[64 * K];
    const int tid  = threadIdx.x;
    const int lane = tid & 63;
    const int wid  = tid >> 6;
    const int c0   = RFL(wid * 16);

    const int ntiles = (M + 63) >> 6;
    for (int t = blockIdx.x; t < ntiles; t += gridDim.x) {
        const int base = t << 6;
        const int rows = MIN(64, M - base);
        __syncthreads();
        {
            const int nw = rows * K;
            const float4* s4 = reinterpret_cast<const float4*>(in + (size_t)base * K);
            const int nv = nw >> 2;
            for (int i = tid; i < nv; i += 256)
                reinterpret_cast<float4*>(xbuf)[i] = s4[i];
            for (int i = (nv << 2) + tid; i < nw; i += 256)
                xbuf[i] = in[(size_t)base * K + i];
        }
        __syncthreads();
        float acc[16];
#pragma unroll
        for (int j = 0; j < 16; ++j) acc[j] = bsum[c0 + j];
        {
            const float sv1 = (lane < rows) ? s1[base + lane] : 0.f;
#pragma unroll
            for (int j = 0; j < 16; ++j) acc[j] = fmaf(sv1, wv1[c0 + j], acc[j]);
        }
        {
            const float* xr = xbuf + lane * K;
#pragma unroll 5
            for (int k = 0; k < K; ++k) {
                const float xk = xr[k];
                const float* wk = Wsum + k * 64 + c0;
#pragma unroll
                for (int j = 0; j < 16; ++j) acc[j] = fmaf(xk, wk[j], acc[j]);
            }
        }
        __syncthreads();
#pragma unroll
        for (int j = 0; j < 16; ++j) xbuf[lane * K + c0 + j] = fmaxf(acc[j], 0.f);
        __syncthreads();
        float a2[16];
#pragma unroll
        for (int j = 0; j < 16; ++j) a2[j] = 0.f;
        {
            const float* hr = xbuf + lane * K;
#pragma unroll 4
            for (int k = 0; k < 64; ++k) {
                const float hk = hr[k];
                const float* wk = W2 + k * 64 + c0;
#pragma unroll
                for (int j = 0; j < 16; ++j) a2[j] = fmaf(hk, wk[j], a2[j]);
            }
        }
        if (lane < rows) {
            float* o0 = out0 + (size_t)(base + lane) * 64 + c0;
#pragma unroll
            for (int j4 = 0; j4 < 4; ++j4)
                reinterpret_cast<float4*>(o0)[j4] =
                    make_float4(a2[4*j4], a2[4*j4+1], a2[4*j4+2], a2[4*j4+3]);
        }
    }
}

// ---------------------------------------------------------------------------
// mega_mfma: all-MFMA transaction pipeline.
// __launch_bounds__(256,4): R15's (256,6) forced VGPR 60->40 and SPILLED the
// accumulators (WRITE_SIZE 3.9->207 MB, 131->186 us). The 2nd arg only caps
// the register budget; it cannot raise runtime residency. Keep 4.
// ---------------------------------------------------------------------------
__global__ __launch_bounds__(256, 4)
void mega_mfma(const unsigned short* __restrict__ xbf, int M,
               const unsigned short* __restrict__ wsumf,
               const unsigned short* __restrict__ w2f,
               const float* __restrict__ b2,     // [4][64], rel 0/1 used
               const float* __restrict__ z1, const float* __restrict__ z2,
               const int* __restrict__ cnt, const unsigned short* __restrict__ adjT,
               int zb0, int zb1, int Nt,
               const float* __restrict__ wl, const float* __restrict__ bl,
               float* __restrict__ out)
{
    __shared__ __align__(16) char ubuf[64 * 68 * 4];   // vbuf f32[64][68] | xb bf16[64][104]
    __shared__ __align__(16) unsigned short hbuf[64 * 72];
    __shared__ float obuf[64][2];
    unsigned short* xb = (unsigned short*)ubuf;
    float*          vbuf = (float*)ubuf;

    const int tid  = threadIdx.x;
    const int lane = tid & 63;
    const int wid  = tid >> 6;
    const int c0   = RFL(wid * 16);
    const bf16x8* wsv = reinterpret_cast<const bf16x8*>(wsumf);
    const bf16x8* w2v = reinterpret_cast<const bf16x8*>(w2f);

    const int ntiles = (M + 63) >> 6;
    for (int t = blockIdx.x; t < ntiles; t += gridDim.x) {
        const int base = t << 6;
        const int rows = MIN(64, M - base);
        __syncthreads();
        // ---- stage: 64 rows x 96 bf16 (12 KB), coalesced 16B units ----
        for (int u = tid; u < 768; u += 256) {
            const int row = u / 12, g = u - row * 12;
            const uint4 d = *reinterpret_cast<const uint4*>(
                xbf + (size_t)(base + row) * 96 + g * 8);
            *reinterpret_cast<uint4*>(xb + row * 104 + g * 8) = d;
        }
        if (tid < 128) ((float*)obuf)[tid] = 0.f;
        __syncthreads();
        // ---- phase 1: acc1 = X~ @ Wsum~  (3 K-steps) ----
        f32x4 acc1[4];
#pragma unroll
        for (int nb = 0; nb < 4; ++nb) acc1[nb] = (f32x4){0.f, 0.f, 0.f, 0.f};
#pragma unroll
        for (int ks = 0; ks < 3; ++ks) {
            const bf16x8 af = *reinterpret_cast<const bf16x8*>(
                xb + (16 * wid + (lane & 15)) * 104 + ks * 32 + ((lane >> 4) << 3));
#pragma unroll
            for (int nb = 0; nb < 4; ++nb) {
                const bf16x8 bf = wsv[(ks * 4 + nb) * 64 + lane];
                acc1[nb] = __builtin_amdgcn_mfma_f32_16x16x32_bf16(af, bf, acc1[nb], 0, 0, 0);
            }
        }
        // ---- H = relu(acc1) -> hbuf bf16 [64][72] (GLOBAL row = 16*wid + local)
#pragma unroll
        for (int nb = 0; nb < 4; ++nb) {
#pragma unroll
            for (int i = 0; i < 4; ++i) {
                const int r = 16 * wid + ((lane >> 4) << 2) + i;
                const int c = (lane & 15) + 16 * nb;
                hbuf[r * 72 + c] = f2bf(fmaxf(acc1[nb][i], 0.f));
            }
        }
        __syncthreads();   // H visible; xb dead (vbuf may overwrite)
        // ---- per relation: phase 2 + transpose + row-pass ----
#pragma unroll 1
        for (int rel = 0; rel < 2; ++rel) {
            f32x4 acc2[4];
#pragma unroll
            for (int nb = 0; nb < 4; ++nb) {
                const float bv = b2[rel * 64 + (lane & 15) + 16 * nb];
                acc2[nb] = (f32x4){bv, bv, bv, bv};
            }
#pragma unroll
            for (int ks = 0; ks < 2; ++ks) {
                const bf16x8 af = *reinterpret_cast<const bf16x8*>(
                    hbuf + (16 * wid + (lane & 15)) * 72 + ks * 32 + ((lane >> 4) << 3));
#pragma unroll
                for (int nb = 0; nb < 4; ++nb) {
                    const bf16x8 bf = w2v[(((rel * 2 + ks) * 4) + nb) * 64 + lane];
                    acc2[nb] = __builtin_amdgcn_mfma_f32_16x16x32_bf16(af, bf, acc2[nb], 0, 0, 0);
                }
            }
            // transpose acc2 -> vbuf [row][col] (pitch 68), GLOBAL row
#pragma unroll
            for (int nb = 0; nb < 4; ++nb) {
#pragma unroll
                for (int i = 0; i < 4; ++i) {
                    const int r = 16 * wid + ((lane >> 4) << 2) + i;
                    const int c = (lane & 15) + 16 * nb;
                    vbuf[r * 68 + c] = acc2[nb][i];
                }
            }
            __syncthreads();
            // row-pass: lane = row, wave covers cols c0..c0+15
            float v[16];
            {
                const float* vr = vbuf + lane * 68 + c0;
#pragma unroll
                for (int q = 0; q < 4; ++q) {
                    const float4 t4 = reinterpret_cast<const float4*>(vr)[q];
                    v[4*q+0] = t4.x; v[4*q+1] = t4.y; v[4*q+2] = t4.z; v[4*q+3] = t4.w;
                }
            }
            if (lane < rows) {
                const int key = (rel ? zb1 : zb0) + base + lane;
                const int n = MIN(cnt[key], CAPT);
                const unsigned short* s = adjT +
                    (size_t)((rel ? Nt : 0) + base + lane) * CAPT;
                const float* zp = rel ? z2 : z1;
                for (int j = 0; j < n; ++j) {
                    const float4* zr = reinterpret_cast<const float4*>(
                        zp + (size_t)s[j] * 64 + c0);
#pragma unroll
                    for (int q = 0; q < 4; ++q) {
                        const float4 zv = zr[q];
                        v[4*q+0] += zv.x; v[4*q+1] += zv.y;
                        v[4*q+2] += zv.z; v[4*q+3] += zv.w;
                    }
                }
            }
            float pa = 0.f, pb = 0.f;
#pragma unroll
            for (int j = 0; j < 16; ++j) {
                const int c = rel * 64 + c0 + j;
                const float vv = fmaxf(v[j], 0.f);
                pa += vv * wl[c * 2 + 0];
                pb += vv * wl[c * 2 + 1];
            }
            atomicAdd(&obuf[lane][0], pa);
            atomicAdd(&obuf[lane][1], pb);
            __syncthreads();   // atomics done; vbuf reusable / obuf stable
        }
        if (tid < 2 * rows) {
            const int r = tid >> 1, o = tid & 1;
            out[(size_t)(base + r) * 2 + o] = obuf[r][o] + bl[o];
        }
    }
}

// ---------------------------------------------------------------------------
extern "C" void kernel_launch(void* const* d_in, const int* in_sizes, int n_in,
                              void* d_out, int out_size, void* d_ws, size_t ws_size,
                              hipStream_t stream)
{
    const float* x_card   = (const float*)d_in[0];
    const float* x_merch  = (const float*)d_in[1];
    const float* x_trans  = (const float*)d_in[2];
    const float* w1_src_t = (const float*)d_in[3];   // [2,1,64]
    const float* w1_dst_t = (const float*)d_in[4];   // [2,85,64]
    const float* b1_t     = (const float*)d_in[5];   // [2,64]
    const float* w1_src_r = (const float*)d_in[6];   // [2,85,64]
    const float* w1_dst_r = (const float*)d_in[7];   // [2,1,64]
    const float* b1_r     = (const float*)d_in[8];   // [2,64]
    const float* w2_l     = (const float*)d_in[9];   // [4,64,64]
    const float* w2_r     = (const float*)d_in[10];  // [4,64,64]
    const float* b2       = (const float*)d_in[11];  // [4,64]
    const float* w_lin    = (const float*)d_in[12];  // [128,2]
    const float* b_lin    = (const float*)d_in[13];  // [2]
    const int*   src_pays = (const int*)d_in[14];
    const int*   dst_pays = (const int*)d_in[15];
    const int*   src_recv = (const int*)d_in[16];
    const int*   dst_recv = (const int*)d_in[17];
    float*       out      = (float*)d_out;

    const int Nc = in_sizes[0];
    const int Nm = in_sizes[1];
    const int Nt = in_sizes[2] / 85;
    const int E  = in_sizes[14];
    const int Ntot = Nc + Nm + 2 * Nt;
    const int ntilesT = (Nt + 63) / 64;
    const int NtP = ntilesT * 64;

    const int baseM = Nc * CAPC;                       // int-bucket offset (merch)
    const size_t adjIntSlots = (size_t)baseM + (size_t)Nm * CAPM;
    const size_t adjTSlots   = (size_t)2 * Nt * CAPT;  // ushort trans buckets

    // workspace layout
    char* wsp = (char*)d_ws;
    auto alloc = [&](size_t bytes) -> void* {
        char* p = wsp;
        wsp += (bytes + 255) & ~(size_t)255;
        return (void*)p;
    };
    int*   cnt    = (int*)alloc((size_t)Ntot * 4);   // bucket cursors
    const size_t zero_bytes = (size_t)(wsp - (char*)d_ws);
    int*   adj    = (int*)alloc(adjIntSlots * 4);
    unsigned short* adjT = (unsigned short*)alloc(adjTSlots * 2);
    float* aggT_c = (float*)alloc((size_t)Nc * 85 * 4);
    float* aggT_m = (float*)alloc((size_t)Nm * 85 * 4);
    unsigned short* xbf   = (unsigned short*)alloc((size_t)NtP * 96 * 2);
    unsigned short* wsumf = (unsigned short*)alloc((size_t)3 * 4 * 64 * 8 * 2);
    unsigned short* w2f   = (unsigned short*)alloc((size_t)2 * 2 * 4 * 64 * 8 * 2);
    float* z1     = (float*)alloc((size_t)Nc * 64 * 4);
    float* z2     = (float*)alloc((size_t)Nm * 64 * 4);
    (void)ws_size; (void)n_in; (void)out_size;

    hipMemsetAsync(d_ws, 0, zero_bytes, stream);   // zero cnt only

    const dim3 blk(256);
    auto tiles = [](int M) { return (M + 63) / 64; };

    // weight fragments + padded bf16 x (slots 85/86 filled after fill)
    prep_wx<<<7, blk, 0, stream>>>(w1_dst_t, b1_t, w1_src_t, w2_r, wsumf, w2f);
    prep_x_main<<<2048, blk, 0, stream>>>(x_trans, Nt, NtP, xbf);

    // ---- bucketed CSR build (8 scattered ops/edge) ----
    fill<<<512, blk, 0, stream>>>(src_pays, dst_pays, src_recv, dst_recv, E, Nc, Nm, Nt,
                                  cnt, adj, adjT, baseM);
    // scalar aggregates by gather
    prep_x_agg<<<2048, blk, 0, stream>>>(x_card, x_merch, cnt, adjT, Nc, Nm, Nt, xbf);

    // ---- conv1 wide aggregation: wave per node, bf16 rows ----
    gather85<<<(Nc + Nm + 3) / 4, blk, 0, stream>>>(
        xbf, cnt, adj, Nc, Nm, baseM, aggT_c, aggT_m);

    // ---- small fused pipelines: aggT -> h -> z ----
    fused_small<<<tiles(Nc), blk, 0, stream>>>(
        aggT_c, Nc, w1_src_r, b1_r, x_card, w1_dst_r, w2_l, z1);
    fused_small<<<tiles(Nm), blk, 0, stream>>>(
        aggT_m, Nm, w1_src_r + 85 * 64, b1_r + 64, x_merch, w1_dst_r + 64,
        w2_l + 64 * 64, z2);

    // ---- MFMA megakernel ----
    mega_mfma<<<ntilesT, blk, 0, stream>>>(
        xbf, Nt, wsumf, w2f, b2, z1, z2,
        cnt, adjT, Nc + Nm, Nc + Nm + Nt, Nt,
        w_lin, b_lin, out);
}